// Round 3
// baseline (1457.484 us; speedup 1.0000x reference)
//
#include <hip/hip_runtime.h>
#include <cstdint>

// SlimmableMoE: B=4,S=1024,D=1024,E=8,F=4096,W=768,H=6,HD=128,TOPK=2
#define NE 8
#define NB 4
#define NS 1024
#define ND 1024
#define NF 4096
#define NW 768
#define NH 6
#define NHD 128
#define NTOK 4096   // B*S
#define NBH 24      // B*H
#define EPS 1e-6f

typedef unsigned short ush;
typedef __attribute__((ext_vector_type(8))) short short8;   // 8 bf16 = 4 VGPR
typedef __attribute__((ext_vector_type(4))) float f32x4;
typedef __attribute__((ext_vector_type(4))) unsigned short u16x4;

typedef const __attribute__((address_space(1))) void gvoid_t;
typedef __attribute__((address_space(3))) void lvoid_t;

__device__ __forceinline__ void gload16(const void* g, void* l) {
  __builtin_amdgcn_global_load_lds((gvoid_t*)g, (lvoid_t*)l, 16, 0, 0);
}

__device__ __forceinline__ ush f2b(float f) {
  union { float f; uint32_t u; } x; x.f = f;
  uint32_t r = x.u + 0x7fffu + ((x.u >> 16) & 1u);
  return (ush)(r >> 16);
}
__device__ __forceinline__ float b2f(ush u) {
  union { uint32_t u; float f; } x; x.u = (uint32_t)u << 16;
  return x.f;
}

// ---------------- cast f32 slice -> bf16 (dst ld = cols) ----------------
__global__ __launch_bounds__(256, 4)
void cast2d(const float* __restrict__ src, int ldsrc, int rows, int cols4,
            ush* __restrict__ dst) {
  long long n = (long long)rows * cols4;
  for (long long idx = (long long)blockIdx.x * blockDim.x + threadIdx.x; idx < n;
       idx += (long long)gridDim.x * blockDim.x) {
    int r = (int)(idx / cols4), c = (int)(idx % cols4);
    float4 v = *(const float4*)(src + (size_t)r * ldsrc + (size_t)c * 4);
    u16x4 o; o.x = f2b(v.x); o.y = f2b(v.y); o.z = f2b(v.z); o.w = f2b(v.w);
    *(u16x4*)(dst + idx * 4) = o;
  }
}

// ---------------- fused per-expert weight cast (6 tensors, 1 launch) ----------------
__global__ __launch_bounds__(256, 4)
void cast_expert(const float* __restrict__ qw, const float* __restrict__ kw,
                 const float* __restrict__ vw, const float* __restrict__ ow,
                 const float* __restrict__ w1, const float* __restrict__ w2,
                 ush* dq, ush* dk, ush* dv, ush* dwo, ush* d1, ush* d2) {
  const int Q4 = 147456;   // 768*768/4
  const int W14 = 786432;  // 4096*768/4  (== 768*4096/4)
  const int total = 4 * Q4 + 2 * W14;
  for (int u = blockIdx.x * 256 + threadIdx.x; u < total; u += gridDim.x * 256) {
    const float* src; ush* dst; int ldsrc, cols4, rel;
    if (u < 4 * Q4) {
      int which = u / Q4; rel = u - which * Q4;
      src = (which == 0) ? qw : (which == 1) ? kw : (which == 2) ? vw : ow;
      dst = (which == 0) ? dq : (which == 1) ? dk : (which == 2) ? dv : dwo;
      ldsrc = 1024; cols4 = 192;
    } else if (u < 4 * Q4 + W14) {
      rel = u - 4 * Q4; src = w1; dst = d1; ldsrc = 1024; cols4 = 192;
    } else {
      rel = u - 4 * Q4 - W14; src = w2; dst = d2; ldsrc = 4096; cols4 = 1024;
    }
    int r = rel / cols4, c = rel - r * cols4;
    float4 v = *(const float4*)(src + (size_t)r * ldsrc + (size_t)c * 4);
    u16x4 o; o.x = f2b(v.x); o.y = f2b(v.y); o.z = f2b(v.z); o.w = f2b(v.w);
    *(u16x4*)(dst + (size_t)rel * 4) = o;
  }
}

// ---------------- router: logits->softmax->top2->normalized gate ----------------
__global__ __launch_bounds__(256, 4)
void router_kernel(const float* __restrict__ x, const float* __restrict__ wr,
                   float* __restrict__ gate) {
  int lane = threadIdx.x & 63, wave = threadIdx.x >> 6;
  int t = blockIdx.x * 4 + wave;
  float acc[NE] = {};
  for (int i = 0; i < 16; ++i) {
    int d = lane + i * 64;
    float xv = x[(size_t)t * ND + d];
    const float* wp = wr + (size_t)d * NE;
    float4 w0 = *(const float4*)wp, w1 = *(const float4*)(wp + 4);
    acc[0] += xv * w0.x; acc[1] += xv * w0.y; acc[2] += xv * w0.z; acc[3] += xv * w0.w;
    acc[4] += xv * w1.x; acc[5] += xv * w1.y; acc[6] += xv * w1.z; acc[7] += xv * w1.w;
  }
#pragma unroll
  for (int e = 0; e < NE; ++e)
    for (int m = 1; m < 64; m <<= 1) acc[e] += __shfl_xor(acc[e], m);
  int i1 = 0; float v1 = acc[0];
#pragma unroll
  for (int e = 1; e < NE; ++e) if (acc[e] > v1) { v1 = acc[e]; i1 = e; }
  int i2 = -1; float v2 = -3.0e38f;
#pragma unroll
  for (int e = 0; e < NE; ++e) if (e != i1 && acc[e] > v2) { v2 = acc[e]; i2 = e; }
  float p2 = __expf(v2 - v1);          // p1 = 1
  float g1 = 1.0f / (1.0f + p2), g2 = p2 / (1.0f + p2);
  if (lane < NE)
    gate[(size_t)t * NE + lane] = (lane == i1) ? g1 : ((lane == i2) ? g2 : 0.0f);
}

// ---------------- per-expert routed-token index lists ----------------
// sections of 1024 rows per batch; idx_all[e*4096 + b*1024 + pos] = token (bit31 = pad)
// cnt64s[e*4+b] = count rounded up to 64
__global__ __launch_bounds__(1024, 1)
void build_index(const float* __restrict__ gate, int* __restrict__ cnt64s,
                 int* __restrict__ idx_all) {
  int e = blockIdx.x >> 2, b = blockIdx.x & 3;
  int s = threadIdx.x, t = b * 1024 + s;
  bool on = gate[(size_t)t * NE + e] > 0.0f;
  idx_all[e * 4096 + t] = (b * 1024) | (int)0x80000000;   // pad default
  __shared__ int wsum[16], wbase[16];
  unsigned long long mask = __ballot(on);
  int lane = s & 63, wv = s >> 6;
  if (lane == 0) wsum[wv] = __popcll(mask);
  __syncthreads();
  if (s == 0) {
    int acc = 0;
    for (int i = 0; i < 16; ++i) { wbase[i] = acc; acc += wsum[i]; }
    cnt64s[e * 4 + b] = (acc + 63) & ~63;
  }
  __syncthreads();
  if (on) {
    int pos = wbase[wv] + __popcll(mask & ((1ull << lane) - 1ull));
    idx_all[e * 4096 + b * 1024 + pos] = t;
  }
}

// ---------------- GEMM: C[M,N] = A[M,K](bf16) * B[N,K](bf16)^T + bias ----------------
// EPI: 0 = bf16 out, 2 = gelu->bf16, 3 = KV fused (z==0: bf16 K; z==1: V^T layout)
// kmode 0: z selects (B,bias,out); kmode 1: split-K, out = out0 + z*M*N, bias only z==0.
// cnt64s (nullable): per-1024-row-section tile early-exit. idxA (nullable): gather A rows.
#define BM 128
#define BN 128
#define BK 64

__device__ __forceinline__ float gelu_exact(float v) {
  return 0.5f * v * (1.0f + erff(v * 0.70710678118654752f));
}

template <int EPI>
__global__ __launch_bounds__(256, 2)
void gemm_bt(const ush* __restrict__ A,
             const ush* B0, const ush* B1,
             const float* bias0, const float* bias1,
             void* out0, void* out1,
             int M, int N, int Kld, int klen, int kmode,
             const int* __restrict__ cnt64s, const int* __restrict__ idxA) {
  const int bm = blockIdx.x, bn = blockIdx.y, z = blockIdx.z;
  if (cnt64s) {
    if (((bm & 7) * 128) >= cnt64s[bm >> 3]) return;
  }
  const ush* Bw; const float* bias; void* outp; int koff;
  if (kmode == 0) {
    Bw = z ? B1 : B0; bias = z ? bias1 : bias0; outp = z ? out1 : out0; koff = 0;
  } else {
    Bw = B0; bias = (z == 0) ? bias0 : nullptr;
    outp = (void*)((ush*)out0 + (size_t)z * M * N); koff = z * klen;
  }

  __shared__ __align__(16) ush As[BM * BK];
  __shared__ __align__(16) ush Bs[BN * BK];

  const int tid = threadIdx.x, lane = tid & 63, wave = tid >> 6;
  const int lr = lane & 15, lg = lane >> 4;
  const int wr = wave >> 1, wc = wave & 1;

  int rowIdx[4];
#pragma unroll
  for (int p = 0; p < 4; ++p) {
    int rrow = bm * BM + p * 32 + (tid >> 3);
    rowIdx[p] = idxA ? (idxA[rrow] & 0x7fffffff) : rrow;
  }

  f32x4 acc[4][4] = {};
  const int nkt = klen / BK;

  for (int kt = 0; kt < nkt; ++kt) {
    __syncthreads();
#pragma unroll
    for (int p = 0; p < 4; ++p) {
      int o = p * 4096 + tid * 16;
      int row = o >> 7, cb = o & 127;
      int cbs = cb ^ ((row & 7) << 4);   // pre-swizzled source (rule #21)
      gload16((const char*)A + ((size_t)rowIdx[p] * Kld + koff + (size_t)kt * BK) * 2 + cbs,
              (char*)As + o);
      gload16((const char*)Bw + ((size_t)(bn * BN + row) * Kld + koff + (size_t)kt * BK) * 2 + cbs,
              (char*)Bs + o);
    }
    __syncthreads();
#pragma unroll
    for (int kk = 0; kk < 2; ++kk) {
      short8 af[4], bfr[4];
#pragma unroll
      for (int i = 0; i < 4; ++i) {
        int rowa = wr * 64 + i * 16 + lr;
        af[i] = *(const short8*)((const char*)As + rowa * 128 +
                                 (((kk * 64 + lg * 16)) ^ ((rowa & 7) << 4)));
        int rowb = wc * 64 + i * 16 + lr;
        bfr[i] = *(const short8*)((const char*)Bs + rowb * 128 +
                                  (((kk * 64 + lg * 16)) ^ ((rowb & 7) << 4)));
      }
#pragma unroll
      for (int i = 0; i < 4; ++i)
#pragma unroll
        for (int j = 0; j < 4; ++j)
          acc[i][j] = __builtin_amdgcn_mfma_f32_16x16x32_bf16(af[i], bfr[j], acc[i][j], 0, 0, 0);
    }
  }

  // epilogue: C row = bm*128+wr*64+i*16+lg*4+r ; col = bn*128+wc*64+j*16+lr
#pragma unroll
  for (int i = 0; i < 4; ++i) {
    int m0 = bm * BM + wr * 64 + i * 16 + lg * 4;
#pragma unroll
    for (int j = 0; j < 4; ++j) {
      int n = bn * BN + wc * 64 + j * 16 + lr;
      float bb = bias ? bias[n] : 0.0f;
      if (EPI == 3 && z == 1) {
        // V^T layout: vt[((b*NH+h)*NHD + d) * NS + s], 4 consecutive s per lane
        int b_ = m0 >> 10, s0 = m0 & 1023, h_ = n >> 7, d = n & 127;
        u16x4 w;
#pragma unroll
        for (int r = 0; r < 4; ++r) w[r] = f2b(acc[i][j][r] + bb);
        *(u16x4*)((ush*)outp + ((size_t)((b_ * NH + h_) * NHD + d)) * NS + s0) = w;
      } else {
        ush* o = (ush*)outp;
#pragma unroll
        for (int r = 0; r < 4; ++r) {
          float v = acc[i][j][r] + bb;
          if (EPI == 2) v = gelu_exact(v);
          o[(size_t)(m0 + r) * N + n] = f2b(v);
        }
      }
    }
  }
}

// ---------------- flash attention: compacted Q rows, KVBLK=64, split-KV x4 ----------------
// grid (16, NBH*4); block 256 = 4 waves; wave owns 16 q rows (compacted); 256 keys/block.
__global__ __launch_bounds__(256, 3)
void attn2(const ush* __restrict__ Qg, const ush* __restrict__ Kg,
           const ush* __restrict__ VTg,
           ush* __restrict__ po, float* __restrict__ mlm, float* __restrict__ mll,
           const int* __restrict__ cnt64s) {
  const int qb = blockIdx.x;
  const int yy = blockIdx.y, bh = yy >> 2, half = yy & 3;
  const int b = bh / NH, h = bh % NH;
  if (qb * 64 >= cnt64s[b]) return;

  __shared__ __align__(16) ush Ks[64 * 128];   // [key][d], rows 256B, swz ^((row&7)<<4)
  __shared__ __align__(16) ush VTs[128 * 64];  // [d][key], rows 128B, swz ^((d&7)<<4)
  __shared__ __align__(16) ush Ps[4 * 16 * 64]; // per-wave 16x64, rows 128B, swz

  const int tid = threadIdx.x, lane = tid & 63, wave = tid >> 6;
  const int lr = lane & 15, lg = lane >> 4;
  const int k0 = half * 256;
  const float cexp = 1.4426950408889634f / sqrtf((float)NHD);

  // Q fragments from compacted rows (row = b*1024 + qb*64 + wave*16 + lr)
  int tq = b * NS + qb * 64 + wave * 16 + lr;
  short8 qf[4];
#pragma unroll
  for (int kk = 0; kk < 4; ++kk)
    qf[kk] = *(const short8*)(Qg + (size_t)tq * NW + h * NHD + kk * 32 + lg * 8);

  f32x4 accv[8] = {};
  float mr[4] = {-3.0e38f, -3.0e38f, -3.0e38f, -3.0e38f};
  float ls[4] = {};

  for (int kt = 0; kt < 4; ++kt) {   // 4 x 64 keys
    __syncthreads();
#pragma unroll
    for (int p = 0; p < 4; ++p) {    // K tile 64x128 (16KB)
      int o = p * 4096 + tid * 16;
      int row = o >> 8, cb = o & 255;
      gload16((const char*)Kg + ((size_t)(b * NS + k0 + kt * 64 + row) * NW + h * NHD) * 2 +
                  (cb ^ ((row & 7) << 4)),
              (char*)Ks + o);
    }
#pragma unroll
    for (int p = 0; p < 4; ++p) {    // V^T tile 128x64 (16KB)
      int o = p * 4096 + tid * 16;
      int d = o >> 7, cb = o & 127;
      gload16((const char*)VTg + ((size_t)(bh * NHD + d) * NS + k0 + kt * 64) * 2 +
                  (cb ^ ((d & 7) << 4)),
              (char*)VTs + o);
    }
    __syncthreads();

    // scores S[q=lg*4+r][key=kg*16+lr]
    f32x4 s[4] = {};
#pragma unroll
    for (int kg = 0; kg < 4; ++kg)
#pragma unroll
      for (int kk = 0; kk < 4; ++kk) {
        int row = kg * 16 + lr;
        short8 kf = *(const short8*)((const char*)Ks + row * 256 +
                                     ((kk * 64 + lg * 16) ^ ((row & 7) << 4)));
        s[kg] = __builtin_amdgcn_mfma_f32_16x16x32_bf16(qf[kk], kf, s[kg], 0, 0, 0);
      }

    // tile max per row
    float mt[4];
#pragma unroll
    for (int r = 0; r < 4; ++r) {
      float m0 = fmaxf(fmaxf(s[0][r], s[1][r]), fmaxf(s[2][r], s[3][r]));
#pragma unroll
      for (int mm = 1; mm < 16; mm <<= 1) m0 = fmaxf(m0, __shfl_xor(m0, mm));
      mt[r] = m0;
    }
    // defer-max: rescale only when some row's max grew past threshold
    bool need = (mt[0] > mr[0] + 8.f) || (mt[1] > mr[1] + 8.f) ||
                (mt[2] > mr[2] + 8.f) || (mt[3] > mr[3] + 8.f);
    if (__any(need)) {
#pragma unroll
      for (int r = 0; r < 4; ++r) {
        float mn = fmaxf(mr[r], mt[r]);
        float sc = exp2f((mr[r] - mn) * cexp);
        mr[r] = mn; ls[r] *= sc;
#pragma unroll
        for (int dg = 0; dg < 8; ++dg) accv[dg][r] *= sc;
      }
    }

    // P -> LDS (per-wave private, swizzled); ls accumulates lane-partial sums
    char* pw = (char*)Ps + wave * 2048;
#pragma unroll
    for (int kg = 0; kg < 4; ++kg)
#pragma unroll
      for (int r = 0; r < 4; ++r) {
        float p = exp2f((s[kg][r] - mr[r]) * cexp);
        ls[r] += p;
        int row = lg * 4 + r;
        *(ush*)(pw + row * 128 + (((kg * 16 + lr) * 2) ^ ((row & 7) << 4))) = f2b(p);
      }
    short8 pf[2];
#pragma unroll
    for (int kk2 = 0; kk2 < 2; ++kk2)
      pf[kk2] = *(const short8*)(pw + lr * 128 + ((kk2 * 64 + lg * 16) ^ ((lr & 7) << 4)));

    // PV: O[q][d] += P(16x64) * V(64x128)
#pragma unroll
    for (int dg = 0; dg < 8; ++dg) {
      int d = dg * 16 + lr;
#pragma unroll
      for (int kk2 = 0; kk2 < 2; ++kk2) {
        short8 vf = *(const short8*)((const char*)VTs + d * 128 +
                                     ((kk2 * 64 + lg * 16) ^ ((d & 7) << 4)));
        accv[dg] = __builtin_amdgcn_mfma_f32_16x16x32_bf16(pf[kk2], vf, accv[dg], 0, 0, 0);
      }
    }
  }

  // reduce lane-partial l across the 16-lane row group (once)
#pragma unroll
  for (int r = 0; r < 4; ++r)
#pragma unroll
    for (int mm = 1; mm < 16; mm <<= 1) ls[r] += __shfl_xor(ls[r], mm);

  // write unnormalized partial O + (m,l)  (rows compacted-local within section)
  size_t base = (size_t)(bh * 4 + half) * NS;
#pragma unroll
  for (int r = 0; r < 4; ++r) {
    int q = qb * 64 + wave * 16 + lg * 4 + r;
#pragma unroll
    for (int dg = 0; dg < 8; ++dg)
      po[(base + q) * NHD + dg * 16 + lr] = f2b(accv[dg][r]);
  }
  if (lr == 0) {
#pragma unroll
    for (int r = 0; r < 4; ++r) {
      int q = qb * 64 + wave * 16 + lg * 4 + r;
      mlm[base + q] = mr[r];
      mll[base + q] = ls[r];
    }
  }
}

// ---------------- combine 4 KV-split partials -> AO (compacted bf16) ----------------
__global__ __launch_bounds__(256, 4)
void attn_combine(const ush* __restrict__ po, const float* __restrict__ mlm,
                  const float* __restrict__ mll, ush* __restrict__ ao,
                  const int* __restrict__ cnt64s) {
  const float cexp = 1.4426950408889634f / sqrtf((float)NHD);
  int idx = blockIdx.x * 256 + threadIdx.x;   // NBH*NS*16 threads
  int row = idx >> 4, dq = idx & 15;
  int bh = row >> 10, q = row & 1023;
  int b = bh / NH, hh = bh % NH;
  if (q >= cnt64s[b]) return;
  float m[4], l[4], M = -3.0e38f;
#pragma unroll
  for (int h = 0; h < 4; ++h) {
    m[h] = mlm[(size_t)(bh * 4 + h) * NS + q];
    l[h] = mll[(size_t)(bh * 4 + h) * NS + q];
    M = fmaxf(M, m[h]);
  }
  float L = 0.0f, w[4];
#pragma unroll
  for (int h = 0; h < 4; ++h) { w[h] = exp2f((m[h] - M) * cexp); L += l[h] * w[h]; }
  float inv = 1.0f / L;
  float o[8] = {};
#pragma unroll
  for (int h = 0; h < 4; ++h) {
    short8 v = *(const short8*)(po + ((size_t)(bh * 4 + h) * NS + q) * NHD + dq * 8);
#pragma unroll
    for (int j = 0; j < 8; ++j) o[j] += b2f((ush)v[j]) * w[h];
  }
  short8 res;
#pragma unroll
  for (int j = 0; j < 8; ++j) res[j] = (short)f2b(o[j] * inv);
  *(short8*)(ao + ((size_t)(b * NS + q)) * NW + hh * NHD + dq * 8) = res;
}

// ---------------- residual + RMSNorm (compacted rows, gathers x) ----------------
__global__ __launch_bounds__(256, 4)
void rmsnorm_res(const float* __restrict__ x, const ush* __restrict__ oo,
                 ush* __restrict__ x1b, const int* __restrict__ cnt64s,
                 const int* __restrict__ idxA) {
  const size_t TOT = (size_t)NTOK * NW;
  int r = blockIdx.x, bsec = r >> 10;
  if ((r & 1023) >= cnt64s[bsec]) return;
  int t = idxA[r] & 0x7fffffff;
  __shared__ float red[4];
  int c = threadIdx.x, lane = c & 63, wave = c >> 6;
  float v[3]; float ss = 0.0f;
#pragma unroll
  for (int i = 0; i < 3; ++i) {
    int col = c + i * 256;
    float a = x[(size_t)t * ND + col] + b2f(oo[(size_t)r * NW + col]) +
              b2f(oo[TOT + (size_t)r * NW + col]);
    v[i] = a; ss += a * a;
  }
#pragma unroll
  for (int m = 1; m < 64; m <<= 1) ss += __shfl_xor(ss, m);
  if (lane == 0) red[wave] = ss;
  __syncthreads();
  float tot = red[0] + red[1] + red[2] + red[3];
  float scale = rsqrtf(tot / (float)NW + EPS);
#pragma unroll
  for (int i = 0; i < 3; ++i) {
    int col = c + i * 256;
    x1b[(size_t)r * NW + col] = f2b(v[i] * scale);
  }
}

// ---------------- final: rmsnorm(x1 + sum(ffp)) * gate -> scatter-add out ----------------
__global__ __launch_bounds__(256, 4)
void final_acc(const ush* __restrict__ x1b, const ush* __restrict__ ffp,
               const float* __restrict__ gate, int e, float* __restrict__ out,
               const int* __restrict__ cnt64s, const int* __restrict__ idxA) {
  const size_t TOT = (size_t)NTOK * NW;
  int r = blockIdx.x, bsec = r >> 10;
  if ((r & 1023) >= cnt64s[bsec]) return;
  int iv = idxA[r];
  if (iv & (int)0x80000000) return;   // pad row
  int t = iv;
  float g = gate[(size_t)t * NE + e];
  __shared__ float red[4];
  int c = threadIdx.x, lane = c & 63, wave = c >> 6;
  float v[3]; float ss = 0.0f;
#pragma unroll
  for (int i = 0; i < 3; ++i) {
    int col = c + i * 256;
    float f = b2f(ffp[(size_t)r * NW + col]) + b2f(ffp[TOT + (size_t)r * NW + col]) +
              b2f(ffp[2 * TOT + (size_t)r * NW + col]) + b2f(ffp[3 * TOT + (size_t)r * NW + col]);
    float a = b2f(x1b[(size_t)r * NW + col]) + f;
    v[i] = a; ss += a * a;
  }
#pragma unroll
  for (int m = 1; m < 64; m <<= 1) ss += __shfl_xor(ss, m);
  if (lane == 0) red[wave] = ss;
  __syncthreads();
  float tot = red[0] + red[1] + red[2] + red[3];
  float scale = rsqrtf(tot / (float)NW + EPS) * g;
#pragma unroll
  for (int i = 0; i < 3; ++i) {
    int col = c + i * 256;
    out[(size_t)t * ND + col] += v[i] * scale;
  }
}

// ---------------- host ----------------
extern "C" void kernel_launch(void* const* d_in, const int* in_sizes, int n_in,
                              void* d_out, int out_size, void* d_ws, size_t ws_size,
                              hipStream_t stream) {
  (void)in_sizes; (void)n_in; (void)ws_size;
  const float* x  = (const float*)d_in[0];
  const float* wr = (const float*)d_in[1];
  const float* qw = (const float*)d_in[2];
  const float* qbias = (const float*)d_in[3];
  const float* kw = (const float*)d_in[4];
  const float* kbias = (const float*)d_in[5];
  const float* vw = (const float*)d_in[6];
  const float* vbias = (const float*)d_in[7];
  const float* ow = (const float*)d_in[8];
  const float* obias = (const float*)d_in[9];
  const float* w1 = (const float*)d_in[10];
  const float* b1 = (const float*)d_in[11];
  const float* w2 = (const float*)d_in[12];
  const float* b2 = (const float*)d_in[13];
  float* out = (float*)d_out;
  char* ws = (char*)d_ws;

  size_t off = 0;
  auto alloc = [&](size_t bytes) {
    void* p = ws + off;
    off += (bytes + 255) & ~(size_t)255;
    return p;
  };
  float* gate = (float*)alloc((size_t)NTOK * NE * 4);
  int* cnt64s = (int*)alloc(NE * NB * 4);
  int* idx_all = (int*)alloc((size_t)NE * NTOK * 4);
  ush* xs  = (ush*)alloc((size_t)NTOK * NW * 2);
  ush* wqb = (ush*)alloc((size_t)NW * NW * 2);
  ush* wkb = (ush*)alloc((size_t)NW * NW * 2);
  ush* wvb = (ush*)alloc((size_t)NW * NW * 2);
  ush* wob = (ush*)alloc((size_t)NW * NW * 2);
  ush* w1b = (ush*)alloc((size_t)NF * NW * 2);
  ush* w2b = (ush*)alloc((size_t)NW * NF * 2);
  ush* x1b = (ush*)alloc((size_t)NTOK * NW * 2);
  // phase-aliased scratch block:
  //  attn phase: [qg 0-6.3M][kg 6.3-12.6][vt 12.6-18.9][po 18.9-44.0][mlm/mll 44.0-44.8][oo 44.8-57.4]
  //              aog aliases qg (combine writes after attn2 consumed qg)
  //  ffn  phase: [hb 0-33.6][ffp 33.6-58.8]
  char* scr = (char*)alloc(58720256 + 1048576);
  ush* qg   = (ush*)scr;
  ush* kg   = (ush*)(scr + 6291456);
  ush* vtg  = (ush*)(scr + 12582912);
  ush* po   = (ush*)(scr + 18874368);
  float* mlm = (float*)(scr + 44040192);
  float* mll = (float*)(scr + 44433408);
  ush* ooP  = (ush*)(scr + 44826624);      // 2 partials x 4096*768 bf16
  ush* aog  = (ush*)scr;                   // combine output over dead qg
  ush* hb   = (ush*)scr;                   // ffn phase
  ush* ffp  = (ush*)(scr + 33554432);      // 4 partials

  hipMemsetAsync(d_out, 0, (size_t)out_size * 4, stream);
  router_kernel<<<dim3(NTOK / 4), 256, 0, stream>>>(x, wr, gate);
  build_index<<<dim3(NE * NB), 1024, 0, stream>>>(gate, cnt64s, idx_all);
  cast2d<<<dim3(1024), 256, 0, stream>>>(x, ND, NTOK, NW / 4, xs);

  for (int e = 0; e < NE; ++e) {
    const int* sec = cnt64s + e * NB;
    const int* idxe = idx_all + (size_t)e * NTOK;
    cast_expert<<<dim3(2048), 256, 0, stream>>>(
        qw + (size_t)e * ND * ND, kw + (size_t)e * ND * ND,
        vw + (size_t)e * ND * ND, ow + (size_t)e * ND * ND,
        w1 + (size_t)e * NF * ND, w2 + (size_t)e * ND * NF,
        wqb, wkb, wvb, wob, w1b, w2b);

    // K,V projections: dense (all tokens are attention keys). z0: K, z1: V->V^T
    gemm_bt<3><<<dim3(32, 6, 2), 256, 0, stream>>>(
        xs, wkb, wvb,
        kbias + (size_t)e * ND, vbias + (size_t)e * ND,
        kg, vtg, NTOK, NW, NW, NW, 0, nullptr, nullptr);

    // Q projection: only routed tokens (gathered A, compacted out)
    gemm_bt<0><<<dim3(32, 6, 1), 256, 0, stream>>>(
        xs, wqb, nullptr,
        qbias + (size_t)e * ND, nullptr,
        qg, nullptr, NTOK, NW, NW, NW, 0, sec, idxe);

    attn2<<<dim3(16, NBH * 4), 256, 0, stream>>>(qg, kg, vtg, po, mlm, mll, sec);
    attn_combine<<<dim3(NBH * NS * 16 / 256), 256, 0, stream>>>(po, mlm, mll, aog, sec);

    // O-proj, split-K x2 -> bf16 partials (compacted rows)
    gemm_bt<0><<<dim3(32, 6, 2), 256, 0, stream>>>(
        aog, wob, nullptr,
        obias + (size_t)e * ND, nullptr,
        ooP, nullptr, NTOK, NW, NW, 384, 1, sec, nullptr);

    rmsnorm_res<<<dim3(NTOK), 256, 0, stream>>>(x, ooP, x1b, sec, idxe);

    // FFN1 (full K, compacted rows)
    gemm_bt<2><<<dim3(32, 32, 1), 256, 0, stream>>>(
        x1b, w1b, nullptr,
        b1 + (size_t)e * NF, nullptr,
        hb, nullptr, NTOK, NF, NW, NW, 0, sec, nullptr);

    // FFN2, split-K x4 -> bf16 partials (compacted rows)
    gemm_bt<0><<<dim3(32, 6, 4), 256, 0, stream>>>(
        hb, w2b, nullptr,
        b2 + (size_t)e * ND, nullptr,
        ffp, nullptr, NTOK, NW, NF, 1024, 1, sec, nullptr);

    final_acc<<<dim3(NTOK), 256, 0, stream>>>(x1b, ffp, gate, e, out, sec, idxe);
  }
}

// Round 5
// 1185.824 us; speedup vs baseline: 1.2291x; 1.2291x over previous
//
#include <hip/hip_runtime.h>
#include <cstdint>

// SlimmableMoE: B=4,S=1024,D=1024,E=8,F=4096,W=768,H=6,HD=128,TOPK=2
#define NE 8
#define NB 4
#define NS 1024
#define ND 1024
#define NF 4096
#define NW 768
#define NH 6
#define NHD 128
#define NTOK 4096   // B*S
#define NBH 24      // B*H
#define RCAP 10496  // compacted-row capacity (max Rtotal=10240 + tile over-read)
#define VSTRIDE ((size_t)NTOK * NW)   // per-expert V^T extent = B*H*HD*S = 3145728
#define EPS 1e-6f

typedef unsigned short ush;
typedef __attribute__((ext_vector_type(8))) short short8;   // 8 bf16 = 4 VGPR
typedef __attribute__((ext_vector_type(4))) float f32x4;
typedef __attribute__((ext_vector_type(4))) unsigned short u16x4;

typedef const __attribute__((address_space(1))) void gvoid_t;
typedef __attribute__((address_space(3))) void lvoid_t;

__device__ __forceinline__ void gload16(const void* g, void* l) {
  __builtin_amdgcn_global_load_lds((gvoid_t*)g, (lvoid_t*)l, 16, 0, 0);
}

__device__ __forceinline__ ush f2b(float f) {
  union { float f; uint32_t u; } x; x.f = f;
  uint32_t r = x.u + 0x7fffu + ((x.u >> 16) & 1u);
  return (ush)(r >> 16);
}
__device__ __forceinline__ float b2f(ush u) {
  union { uint32_t u; float f; } x; x.u = (uint32_t)u << 16;
  return x.f;
}
__device__ __forceinline__ int prefix_sum(const int* __restrict__ c, int n) {
  int s = 0;
#pragma unroll 1
  for (int i = 0; i < n; ++i) s += c[i];
  return s;
}

// ---------------- router: logits->softmax->top2->gate; init inv map ----------------
__global__ __launch_bounds__(256, 4)
void router_kernel(const float* __restrict__ x, const float* __restrict__ wr,
                   float* __restrict__ gate, int* __restrict__ inv) {
  int lane = threadIdx.x & 63, wave = threadIdx.x >> 6;
  int t = blockIdx.x * 4 + wave;
  float acc[NE] = {};
  for (int i = 0; i < 16; ++i) {
    int d = lane + i * 64;
    float xv = x[(size_t)t * ND + d];
    const float* wp = wr + (size_t)d * NE;
    float4 w0 = *(const float4*)wp, w1 = *(const float4*)(wp + 4);
    acc[0] += xv * w0.x; acc[1] += xv * w0.y; acc[2] += xv * w0.z; acc[3] += xv * w0.w;
    acc[4] += xv * w1.x; acc[5] += xv * w1.y; acc[6] += xv * w1.z; acc[7] += xv * w1.w;
  }
#pragma unroll
  for (int e = 0; e < NE; ++e)
    for (int m = 1; m < 64; m <<= 1) acc[e] += __shfl_xor(acc[e], m);
  int i1 = 0; float v1 = acc[0];
#pragma unroll
  for (int e = 1; e < NE; ++e) if (acc[e] > v1) { v1 = acc[e]; i1 = e; }
  int i2 = -1; float v2 = -3.0e38f;
#pragma unroll
  for (int e = 0; e < NE; ++e) if (e != i1 && acc[e] > v2) { v2 = acc[e]; i2 = e; }
  float p2 = __expf(v2 - v1);          // p1 = 1
  float g1 = 1.0f / (1.0f + p2), g2 = p2 / (1.0f + p2);
  if (lane < NE)
    gate[(size_t)t * NE + lane] = (lane == i1) ? g1 : ((lane == i2) ? g2 : 0.0f);
  if (lane < 2) inv[t * 2 + lane] = -1;
}

// ---------------- per-expert routed-token index lists + inverse map ----------------
// idx_all[(e*4+b)*1024 + pos] = token (bit31 = pad); cnt64s[e*4+b] = cnt rounded to 64
// inv[t*2+k] = (e<<12)|pos, slots ordered by expert id
__global__ __launch_bounds__(1024, 1)
void build_index(const float* __restrict__ gate, int* __restrict__ cnt64s,
                 int* __restrict__ idx_all, int* __restrict__ inv) {
  int e = blockIdx.x >> 2, b = blockIdx.x & 3;
  int s = threadIdx.x, t = b * 1024 + s;
  bool on = gate[(size_t)t * NE + e] > 0.0f;
  idx_all[(e * 4 + b) * 1024 + s] = (b * 1024) | (int)0x80000000;   // pad default
  __shared__ int wsum[16], wbase[16];
  unsigned long long mask = __ballot(on);
  int lane = s & 63, wv = s >> 6;
  if (lane == 0) wsum[wv] = __popcll(mask);
  __syncthreads();
  if (s == 0) {
    int acc = 0;
    for (int i = 0; i < 16; ++i) { wbase[i] = acc; acc += wsum[i]; }
    cnt64s[e * 4 + b] = (acc + 63) & ~63;
  }
  __syncthreads();
  if (on) {
    int pos = wbase[wv] + __popcll(mask & ((1ull << lane) - 1ull));
    idx_all[(e * 4 + b) * 1024 + pos] = t;
    int k = 0;
#pragma unroll
    for (int j = 0; j < NE; ++j) k += (j < e && gate[(size_t)t * NE + j] > 0.0f);
    inv[t * 2 + k] = (e << 12) | pos;
  }
}

// ---------------- all casts f32->bf16 in one launch: y=0..7 expert weights, y=8 xs ----------------
__global__ __launch_bounds__(256, 4)
void cast_all(const float* __restrict__ x,
              const float* __restrict__ qw, const float* __restrict__ kw,
              const float* __restrict__ vw, const float* __restrict__ ow,
              const float* __restrict__ w1, const float* __restrict__ w2,
              ush* __restrict__ xs,
              ush* __restrict__ dq, ush* __restrict__ dk, ush* __restrict__ dv,
              ush* __restrict__ dwo, ush* __restrict__ d1, ush* __restrict__ d2) {
  int y = blockIdx.y;
  if (y == 8) {
    const int n4 = NTOK * NW / 4;
    for (int u = blockIdx.x * 256 + threadIdx.x; u < n4; u += gridDim.x * 256) {
      int r = u / (NW / 4), c = u - r * (NW / 4);
      float4 v = *(const float4*)(x + (size_t)r * ND + c * 4);
      u16x4 o; o.x = f2b(v.x); o.y = f2b(v.y); o.z = f2b(v.z); o.w = f2b(v.w);
      *(u16x4*)(xs + (size_t)u * 4) = o;
    }
    return;
  }
  const int e = y;
  const int Q4 = 147456;   // 768*768/4
  const int W14 = 786432;  // 4096*768/4
  const int total = 4 * Q4 + 2 * W14;
  const float* qe = qw + (size_t)e * ND * ND;
  const float* ke = kw + (size_t)e * ND * ND;
  const float* ve = vw + (size_t)e * ND * ND;
  const float* oe = ow + (size_t)e * ND * ND;
  const float* w1e = w1 + (size_t)e * NF * ND;
  const float* w2e = w2 + (size_t)e * ND * NF;
  ush* dqe = dq + (size_t)e * NW * NW;
  ush* dke = dk + (size_t)e * NW * NW;
  ush* dve = dv + (size_t)e * NW * NW;
  ush* doe = dwo + (size_t)e * NW * NW;
  ush* d1e = d1 + (size_t)e * NF * NW;
  ush* d2e = d2 + (size_t)e * NW * NF;
  for (int u = blockIdx.x * 256 + threadIdx.x; u < total; u += gridDim.x * 256) {
    const float* src; ush* dst; int ldsrc, cols4, rel;
    if (u < 4 * Q4) {
      int which = u / Q4; rel = u - which * Q4;
      src = (which == 0) ? qe : (which == 1) ? ke : (which == 2) ? ve : oe;
      dst = (which == 0) ? dqe : (which == 1) ? dke : (which == 2) ? dve : doe;
      ldsrc = 1024; cols4 = 192;
    } else if (u < 4 * Q4 + W14) {
      rel = u - 4 * Q4; src = w1e; dst = d1e; ldsrc = 1024; cols4 = 192;
    } else {
      rel = u - 4 * Q4 - W14; src = w2e; dst = d2e; ldsrc = 4096; cols4 = 1024;
    }
    int r = rel / cols4, c = rel - r * cols4;
    float4 v = *(const float4*)(src + (size_t)r * ldsrc + (size_t)c * 4);
    u16x4 o; o.x = f2b(v.x); o.y = f2b(v.y); o.z = f2b(v.z); o.w = f2b(v.w);
    *(u16x4*)(dst + (size_t)rel * 4) = o;
  }
}

#define BM 128
#define BN 128
#define BK 64

__device__ __forceinline__ float gelu_exact(float v) {
  return 0.5f * v * (1.0f + erff(v * 0.70710678118654752f));
}

// ---------------- batched QKV GEMM: grid (32,6,24); z = e*3 + {0:Q(compact),1:K,2:V^T} ----------------
__global__ __launch_bounds__(256, 2)
void qkv_gemm(const ush* __restrict__ A,
              const ush* __restrict__ wqb, const ush* __restrict__ wkb,
              const ush* __restrict__ wvb,
              const float* __restrict__ qbias, const float* __restrict__ kbias,
              const float* __restrict__ vbias,
              ush* __restrict__ qg, ush* __restrict__ kg, ush* __restrict__ vtg,
              const int* __restrict__ cnt64s, const int* __restrict__ idx_all) {
  const int bm = blockIdx.x, bn = blockIdx.y, z = blockIdx.z;
  const int e = z / 3, w = z - e * 3;
  int sb = 0, cnt = 0;
  if (w == 0) {
    int sec = e * 4 + (bm >> 3);
    cnt = cnt64s[sec];
    if (((bm & 7) * 128) >= cnt) return;
    sb = prefix_sum(cnt64s, sec);
  }
  const ush* Bw = ((w == 0) ? wqb : (w == 1) ? wkb : wvb) + (size_t)e * NW * NW;
  const float* bias = ((w == 0) ? qbias : (w == 1) ? kbias : vbias) + (size_t)e * ND;

  __shared__ __align__(16) ush As[BM * BK];
  __shared__ __align__(16) ush Bs[BN * BK];

  const int tid = threadIdx.x, lane = tid & 63, wave = tid >> 6;
  const int lr = lane & 15, lg = lane >> 4;
  const int wr = wave >> 1, wc = wave & 1;

  int rowIdx[4];
#pragma unroll
  for (int p = 0; p < 4; ++p) {
    if (w == 0) {
      int lrow = (bm & 7) * 128 + p * 32 + (tid >> 3);
      rowIdx[p] = idx_all[(e * 4 + (bm >> 3)) * 1024 + lrow] & 0x7fffffff;
    } else {
      rowIdx[p] = bm * BM + p * 32 + (tid >> 3);
    }
  }

  f32x4 acc[4][4] = {};
  for (int kt = 0; kt < NW / BK; ++kt) {
    __syncthreads();
#pragma unroll
    for (int p = 0; p < 4; ++p) {
      int o = p * 4096 + tid * 16;
      int row = o >> 7, cb = o & 127;
      int cbs = cb ^ ((row & 7) << 4);
      gload16((const char*)A + ((size_t)rowIdx[p] * NW + (size_t)kt * BK) * 2 + cbs,
              (char*)As + o);
      gload16((const char*)Bw + ((size_t)(bn * BN + row) * NW + (size_t)kt * BK) * 2 + cbs,
              (char*)Bs + o);
    }
    __syncthreads();
#pragma unroll
    for (int kk = 0; kk < 2; ++kk) {
      short8 af[4], bfr[4];
#pragma unroll
      for (int i = 0; i < 4; ++i) {
        int rowa = wr * 64 + i * 16 + lr;
        af[i] = *(const short8*)((const char*)As + rowa * 128 +
                                 (((kk * 64 + lg * 16)) ^ ((rowa & 7) << 4)));
        int rowb = wc * 64 + i * 16 + lr;
        bfr[i] = *(const short8*)((const char*)Bs + rowb * 128 +
                                  (((kk * 64 + lg * 16)) ^ ((rowb & 7) << 4)));
      }
#pragma unroll
      for (int i = 0; i < 4; ++i)
#pragma unroll
        for (int j = 0; j < 4; ++j)
          acc[i][j] = __builtin_amdgcn_mfma_f32_16x16x32_bf16(af[i], bfr[j], acc[i][j], 0, 0, 0);
    }
  }

#pragma unroll
  for (int i = 0; i < 4; ++i) {
    int lm16 = (bm & 7) * 128 + wr * 64 + i * 16;            // Q: section-local 16-row group
    int m0 = bm * BM + wr * 64 + i * 16 + lg * 4;            // dense row
#pragma unroll
    for (int j = 0; j < 4; ++j) {
      int n = bn * BN + wc * 64 + j * 16 + lr;
      float bb = bias[n];
      if (w == 0) {
        if (lm16 < cnt) {
          int grow = sb + lm16 + lg * 4;
#pragma unroll
          for (int r = 0; r < 4; ++r)
            qg[(size_t)(grow + r) * NW + n] = f2b(acc[i][j][r] + bb);
        }
      } else if (w == 1) {
        ush* o = kg + (size_t)e * NTOK * NW;
#pragma unroll
        for (int r = 0; r < 4; ++r)
          o[(size_t)(m0 + r) * NW + n] = f2b(acc[i][j][r] + bb);
      } else {
        int b_ = m0 >> 10, s0 = m0 & 1023, h_ = n >> 7, d = n & 127;
        u16x4 wv_;
#pragma unroll
        for (int r = 0; r < 4; ++r) wv_[r] = f2b(acc[i][j][r] + bb);
        *(u16x4*)(vtg + (size_t)e * VSTRIDE +
                  ((size_t)(b_ * NH + h_) * NHD + d) * NS + s0) = wv_;
      }
    }
  }
}

// ---------------- batched flash attention: grid (16, 96, 8) ----------------
__global__ __launch_bounds__(256, 3)
void attn2(const ush* __restrict__ Qg, const ush* __restrict__ Kg,
           const ush* __restrict__ VTg,
           ush* __restrict__ po, float* __restrict__ mlm, float* __restrict__ mll,
           const int* __restrict__ cnt64s) {
  const int qb = blockIdx.x, yy = blockIdx.y, e = blockIdx.z;
  const int bh = yy >> 2, half = yy & 3;
  const int b = bh / NH, h = bh % NH;
  const int sec = e * 4 + b;
  const int cnt = cnt64s[sec];
  if (qb * 64 >= cnt) return;
  const int sb = prefix_sum(cnt64s, sec);

  __shared__ __align__(16) ush Ks[64 * 128];
  __shared__ __align__(16) ush VTs[128 * 64];
  __shared__ __align__(16) ush Ps[4 * 16 * 64];

  const int tid = threadIdx.x, lane = tid & 63, wave = tid >> 6;
  const int lr = lane & 15, lg = lane >> 4;
  const int k0 = half * 256;
  const float cexp = 1.4426950408889634f / sqrtf((float)NHD);

  const ush* Ke = Kg + (size_t)e * NTOK * NW;
  const ush* Ve = VTg + (size_t)e * VSTRIDE;

  int growq = sb + qb * 64 + wave * 16 + lr;
  short8 qf[4];
#pragma unroll
  for (int kk = 0; kk < 4; ++kk)
    qf[kk] = *(const short8*)(Qg + (size_t)growq * NW + h * NHD + kk * 32 + lg * 8);

  f32x4 accv[8] = {};
  float mr[4] = {-3.0e38f, -3.0e38f, -3.0e38f, -3.0e38f};
  float ls[4] = {};

  for (int kt = 0; kt < 4; ++kt) {
    __syncthreads();
#pragma unroll
    for (int p = 0; p < 4; ++p) {
      int o = p * 4096 + tid * 16;
      int row = o >> 8, cb = o & 255;
      gload16((const char*)Ke + ((size_t)(b * NS + k0 + kt * 64 + row) * NW + h * NHD) * 2 +
                  (cb ^ ((row & 7) << 4)),
              (char*)Ks + o);
    }
#pragma unroll
    for (int p = 0; p < 4; ++p) {
      int o = p * 4096 + tid * 16;
      int d = o >> 7, cb = o & 127;
      gload16((const char*)Ve + ((size_t)((b * NH + h) * NHD + d) * NS + k0 + kt * 64) * 2 +
                  (cb ^ ((d & 7) << 4)),
              (char*)VTs + o);
    }
    __syncthreads();

    f32x4 s[4] = {};
#pragma unroll
    for (int kg2 = 0; kg2 < 4; ++kg2)
#pragma unroll
      for (int kk = 0; kk < 4; ++kk) {
        int row = kg2 * 16 + lr;
        short8 kf = *(const short8*)((const char*)Ks + row * 256 +
                                     ((kk * 64 + lg * 16) ^ ((row & 7) << 4)));
        s[kg2] = __builtin_amdgcn_mfma_f32_16x16x32_bf16(qf[kk], kf, s[kg2], 0, 0, 0);
      }

    float mt[4];
#pragma unroll
    for (int r = 0; r < 4; ++r) {
      float m0 = fmaxf(fmaxf(s[0][r], s[1][r]), fmaxf(s[2][r], s[3][r]));
#pragma unroll
      for (int mm = 1; mm < 16; mm <<= 1) m0 = fmaxf(m0, __shfl_xor(m0, mm));
      mt[r] = m0;
    }
    bool need = (mt[0] > mr[0] + 8.f) || (mt[1] > mr[1] + 8.f) ||
                (mt[2] > mr[2] + 8.f) || (mt[3] > mr[3] + 8.f);
    if (__any(need)) {
#pragma unroll
      for (int r = 0; r < 4; ++r) {
        float mn = fmaxf(mr[r], mt[r]);
        float sc = exp2f((mr[r] - mn) * cexp);
        mr[r] = mn; ls[r] *= sc;
#pragma unroll
        for (int dg = 0; dg < 8; ++dg) accv[dg][r] *= sc;
      }
    }

    char* pw = (char*)Ps + wave * 2048;
#pragma unroll
    for (int kg2 = 0; kg2 < 4; ++kg2)
#pragma unroll
      for (int r = 0; r < 4; ++r) {
        float p = exp2f((s[kg2][r] - mr[r]) * cexp);
        ls[r] += p;
        int row = lg * 4 + r;
        *(ush*)(pw + row * 128 + (((kg2 * 16 + lr) * 2) ^ ((row & 7) << 4))) = f2b(p);
      }
    short8 pf[2];
#pragma unroll
    for (int kk2 = 0; kk2 < 2; ++kk2)
      pf[kk2] = *(const short8*)(pw + lr * 128 + ((kk2 * 64 + lg * 16) ^ ((lr & 7) << 4)));

#pragma unroll
    for (int dg = 0; dg < 8; ++dg) {
      int d = dg * 16 + lr;
#pragma unroll
      for (int kk2 = 0; kk2 < 2; ++kk2) {
        short8 vf = *(const short8*)((const char*)VTs + d * 128 +
                                     ((kk2 * 64 + lg * 16) ^ ((d & 7) << 4)));
        accv[dg] = __builtin_amdgcn_mfma_f32_16x16x32_bf16(pf[kk2], vf, accv[dg], 0, 0, 0);
      }
    }
  }

#pragma unroll
  for (int r = 0; r < 4; ++r)
#pragma unroll
    for (int mm = 1; mm < 16; mm <<= 1) ls[r] += __shfl_xor(ls[r], mm);

#pragma unroll
  for (int r = 0; r < 4; ++r) {
    int growr = sb + qb * 64 + wave * 16 + lg * 4 + r;
#pragma unroll
    for (int dg = 0; dg < 8; ++dg)
      po[((size_t)(growr * NH + h) * 4 + half) * NHD + dg * 16 + lr] = f2b(accv[dg][r]);
  }
  if (lr == 0) {
#pragma unroll
    for (int r = 0; r < 4; ++r) {
      int growr = sb + qb * 64 + wave * 16 + lg * 4 + r;
      mlm[(size_t)(growr * NH + h) * 4 + half] = mr[r];
      mll[(size_t)(growr * NH + h) * 4 + half] = ls[r];
    }
  }
}

// ---------------- combine 4 KV-split partials -> AO rows (compacted) ----------------
__global__ __launch_bounds__(256, 4)
void attn_combine(const ush* __restrict__ po, const float* __restrict__ mlm,
                  const float* __restrict__ mll, ush* __restrict__ ao,
                  const int* __restrict__ cnt64s) {
  const float cexp = 1.4426950408889634f / sqrtf((float)NHD);
  int Rtot = prefix_sum(cnt64s, 32);
  int idx = blockIdx.x * 256 + threadIdx.x;
  int row = idx >> 4, dq = idx & 15;
  int grow = row / NH, h = row - grow * NH;
  if (grow >= Rtot) return;
  float m[4], l[4], M = -3.0e38f;
#pragma unroll
  for (int hh = 0; hh < 4; ++hh) {
    m[hh] = mlm[(size_t)row * 4 + hh];
    l[hh] = mll[(size_t)row * 4 + hh];
    M = fmaxf(M, m[hh]);
  }
  float L = 0.0f, w[4];
#pragma unroll
  for (int hh = 0; hh < 4; ++hh) { w[hh] = exp2f((m[hh] - M) * cexp); L += l[hh] * w[hh]; }
  float inv_ = 1.0f / L;
  float o[8] = {};
#pragma unroll
  for (int hh = 0; hh < 4; ++hh) {
    short8 v = *(const short8*)(po + ((size_t)row * 4 + hh) * NHD + dq * 8);
#pragma unroll
    for (int j = 0; j < 8; ++j) o[j] += b2f((ush)v[j]) * w[hh];
  }
  short8 res;
#pragma unroll
  for (int j = 0; j < 8; ++j) res[j] = (short)f2b(o[j] * inv_);
  *(short8*)(ao + (size_t)grow * NW + h * NHD + dq * 8) = res;
}

// ---------------- CSR GEMM (batched over experts + optional split-K) ----------------
// grid (32, N/128, 8*nsplit); z = e*nsplit + s; rows = expert-compacted [ebase, ebase+Re)
template <int EPI>   // 0 = bf16 out, 2 = gelu->bf16
__global__ __launch_bounds__(256, 2)
void csr_gemm(const ush* __restrict__ A, const ush* __restrict__ Ball,
              const float* __restrict__ biasAll, ush* __restrict__ out,
              int N, int Kld, int klen, int nsplit, int strideBe, int biasStride,
              const int* __restrict__ cnt64s) {
  const int bm = blockIdx.x, bn = blockIdx.y, z = blockIdx.z;
  const int e = z / nsplit, s = z - e * nsplit;
  const int Re = cnt64s[e * 4] + cnt64s[e * 4 + 1] + cnt64s[e * 4 + 2] + cnt64s[e * 4 + 3];
  if (bm * BM >= Re) return;
  const int ebase = prefix_sum(cnt64s, e * 4);
  const ush* Bw = Ball + (size_t)e * strideBe;
  const float* bias = (s == 0) ? biasAll + (size_t)e * biasStride : nullptr;
  const int koff = s * klen;
  ush* outp = out + (size_t)s * RCAP * N;

  __shared__ __align__(16) ush As[BM * BK];
  __shared__ __align__(16) ush Bs[BN * BK];

  const int tid = threadIdx.x, lane = tid & 63, wave = tid >> 6;
  const int lr = lane & 15, lg = lane >> 4;
  const int wr = wave >> 1, wc = wave & 1;

  f32x4 acc[4][4] = {};
  const int nkt = klen / BK;
  for (int kt = 0; kt < nkt; ++kt) {
    __syncthreads();
#pragma unroll
    for (int p = 0; p < 4; ++p) {
      int o = p * 4096 + tid * 16;
      int row = o >> 7, cb = o & 127;
      int cbs = cb ^ ((row & 7) << 4);
      gload16((const char*)A + ((size_t)(ebase + bm * BM + row) * Kld + koff + (size_t)kt * BK) * 2 + cbs,
              (char*)As + o);
      gload16((const char*)Bw + ((size_t)(bn * BN + row) * Kld + koff + (size_t)kt * BK) * 2 + cbs,
              (char*)Bs + o);
    }
    __syncthreads();
#pragma unroll
    for (int kk = 0; kk < 2; ++kk) {
      short8 af[4], bfr[4];
#pragma unroll
      for (int i = 0; i < 4; ++i) {
        int rowa = wr * 64 + i * 16 + lr;
        af[i] = *(const short8*)((const char*)As + rowa * 128 +
                                 (((kk * 64 + lg * 16)) ^ ((rowa & 7) << 4)));
        int rowb = wc * 64 + i * 16 + lr;
        bfr[i] = *(const short8*)((const char*)Bs + rowb * 128 +
                                  (((kk * 64 + lg * 16)) ^ ((rowb & 7) << 4)));
      }
#pragma unroll
      for (int i = 0; i < 4; ++i)
#pragma unroll
        for (int j = 0; j < 4; ++j)
          acc[i][j] = __builtin_amdgcn_mfma_f32_16x16x32_bf16(af[i], bfr[j], acc[i][j], 0, 0, 0);
    }
  }

#pragma unroll
  for (int i = 0; i < 4; ++i) {
    int lm16 = bm * BM + wr * 64 + i * 16;
    if (lm16 >= Re) continue;                  // cross-expert guard (Re % 64 == 0)
#pragma unroll
    for (int j = 0; j < 4; ++j) {
      int n = bn * BN + wc * 64 + j * 16 + lr;
      float bb = bias ? bias[n] : 0.0f;
      int row0 = ebase + lm16 + lg * 4;
#pragma unroll
      for (int r = 0; r < 4; ++r) {
        float v = acc[i][j][r] + bb;
        if (EPI == 2) v = gelu_exact(v);
        outp[(size_t)(row0 + r) * N + n] = f2b(v);
      }
    }
  }
}

// ---------------- residual + RMSNorm over compacted rows ----------------
__global__ __launch_bounds__(256, 4)
void rmsnorm_res(const float* __restrict__ x, const ush* __restrict__ ooP,
                 ush* __restrict__ x1b, const int* __restrict__ cnt64s,
                 const int* __restrict__ idx_all) {
  int r = blockIdx.x;
  int base = 0, sec = -1, loc = 0;
#pragma unroll 1
  for (int i = 0; i < 32; ++i) {
    int cc = cnt64s[i];
    if (sec < 0 && r < base + cc) { sec = i; loc = r - base; }
    base += cc;
  }
  if (sec < 0) return;
  int t = idx_all[sec * 1024 + loc] & 0x7fffffff;
  __shared__ float red[4];
  int c = threadIdx.x, lane = c & 63, wave = c >> 6;
  float v[3]; float ss = 0.0f;
#pragma unroll
  for (int i = 0; i < 3; ++i) {
    int col = c + i * 256;
    float a = x[(size_t)t * ND + col] + b2f(ooP[(size_t)r * NW + col]) +
              b2f(ooP[(size_t)RCAP * NW + (size_t)r * NW + col]);
    v[i] = a; ss += a * a;
  }
#pragma unroll
  for (int m = 1; m < 64; m <<= 1) ss += __shfl_xor(ss, m);
  if (lane == 0) red[wave] = ss;
  __syncthreads();
  float tot = red[0] + red[1] + red[2] + red[3];
  float scale = rsqrtf(tot / (float)NW + EPS);
#pragma unroll
  for (int i = 0; i < 3; ++i) {
    int col = c + i * 256;
    x1b[(size_t)r * NW + col] = f2b(v[i] * scale);
  }
}

// ---------------- final: per token, gather both experts, rmsnorm, gate-sum, write out ----------------
__global__ __launch_bounds__(256, 4)
void final_token(const ush* __restrict__ x1b, const ush* __restrict__ ffp,
                 const float* __restrict__ gate, const int* __restrict__ inv,
                 const int* __restrict__ cnt64s, float* __restrict__ out) {
  int t = blockIdx.x, c = threadIdx.x, lane = c & 63, wave = c >> 6;
  __shared__ float red[4];
  float acc[3] = {0.0f, 0.0f, 0.0f};
#pragma unroll 1
  for (int k = 0; k < 2; ++k) {
    int v = inv[t * 2 + k];
    if (v >= 0) {
      int e = v >> 12, pos = v & 0xfff;
      int b = t >> 10;
      int grow = prefix_sum(cnt64s, e * 4 + b) + pos;
      float g = gate[(size_t)t * NE + e];
      float vv[3]; float ss = 0.0f;
#pragma unroll
      for (int i = 0; i < 3; ++i) {
        int col = c + i * 256;
        float f = b2f(ffp[(size_t)grow * NW + col]) +
                  b2f(ffp[(size_t)RCAP * NW + (size_t)grow * NW + col]) +
                  b2f(ffp[2 * (size_t)RCAP * NW + (size_t)grow * NW + col]) +
                  b2f(ffp[3 * (size_t)RCAP * NW + (size_t)grow * NW + col]);
        float a = b2f(x1b[(size_t)grow * NW + col]) + f;
        vv[i] = a; ss += a * a;
      }
#pragma unroll
      for (int m = 1; m < 64; m <<= 1) ss += __shfl_xor(ss, m);
      if (lane == 0) red[wave] = ss;
      __syncthreads();
      float tot = red[0] + red[1] + red[2] + red[3];
      float scale = rsqrtf(tot / (float)NW + EPS) * g;
#pragma unroll
      for (int i = 0; i < 3; ++i) acc[i] += vv[i] * scale;
      __syncthreads();
    }
  }
#pragma unroll
  for (int i = 0; i < 3; ++i) out[(size_t)t * ND + c + i * 256] = acc[i];
  out[(size_t)t * ND + 768 + c] = 0.0f;
}

// ---------------- host ----------------
extern "C" void kernel_launch(void* const* d_in, const int* in_sizes, int n_in,
                              void* d_out, int out_size, void* d_ws, size_t ws_size,
                              hipStream_t stream) {
  (void)in_sizes; (void)n_in; (void)ws_size; (void)out_size;
  const float* x  = (const float*)d_in[0];
  const float* wr = (const float*)d_in[1];
  const float* qw = (const float*)d_in[2];
  const float* qbias = (const float*)d_in[3];
  const float* kw = (const float*)d_in[4];
  const float* kbias = (const float*)d_in[5];
  const float* vw = (const float*)d_in[6];
  const float* vbias = (const float*)d_in[7];
  const float* ow = (const float*)d_in[8];
  const float* obias = (const float*)d_in[9];
  const float* w1 = (const float*)d_in[10];
  const float* b1 = (const float*)d_in[11];
  const float* w2 = (const float*)d_in[12];
  const float* b2 = (const float*)d_in[13];
  float* out = (float*)d_out;
  char* ws = (char*)d_ws;

  size_t off = 0;
  auto alloc = [&](size_t bytes) {
    void* p = ws + off;
    off += (bytes + 255) & ~(size_t)255;
    return p;
  };
  float* gate = (float*)alloc((size_t)NTOK * NE * 4);
  int* cnt64s = (int*)alloc(32 * 4);
  int* idx_all = (int*)alloc((size_t)NE * NTOK * 4);
  int* inv = (int*)alloc((size_t)NTOK * 2 * 4);
  ush* xs  = (ush*)alloc((size_t)NTOK * NW * 2);
  ush* wqb = (ush*)alloc((size_t)NE * NW * NW * 2);
  ush* wkb = (ush*)alloc((size_t)NE * NW * NW * 2);
  ush* wvb = (ush*)alloc((size_t)NE * NW * NW * 2);
  ush* wob = (ush*)alloc((size_t)NE * NW * NW * 2);
  ush* w1b = (ush*)alloc((size_t)NE * NF * NW * 2);
  ush* w2b = (ush*)alloc((size_t)NE * NW * NF * 2);
  ush* x1b = (ush*)alloc((size_t)RCAP * NW * 2);
  // arena1: attn {qg, po, mlm, mll} -> ffn {hb}
  char* arena1 = (char*)alloc((size_t)RCAP * NF * 2);          // 86.0 MB
  ush* qg  = (ush*)arena1;                                      // RCAP*768*2 = 16.1 MB
  ush* po  = (ush*)(arena1 + 16121856);                         // RCAP*24*128*2 = 64.5 MB
  float* mlm = (float*)(arena1 + 80609280);                     // RCAP*24*4 = 1.0 MB
  float* mll = (float*)(arena1 + 81616896);
  ush* hb  = (ush*)arena1;                                      // RCAP*4096*2
  // arena2: attn {kg, vtg} -> post {aog, ooP, ffp}
  char* arena2 = (char*)alloc(112852992);
  ush* kg  = (ush*)arena2;                                      // 8*4096*768*2 = 50.3 MB
  ush* vtg = (ush*)(arena2 + 50331648);                         // 50.3 MB
  ush* aog = (ush*)arena2;                                      // RCAP*768*2
  ush* ooP = (ush*)(arena2 + 16121856);                         // 2 partials
  ush* ffp = (ush*)(arena2 + 48365568);                         // 4 partials

  router_kernel<<<dim3(NTOK / 4), 256, 0, stream>>>(x, wr, gate, inv);
  build_index<<<dim3(NE * NB), 1024, 0, stream>>>(gate, cnt64s, idx_all, inv);
  cast_all<<<dim3(288, 9), 256, 0, stream>>>(x, qw, kw, vw, ow, w1, w2,
                                             xs, wqb, wkb, wvb, wob, w1b, w2b);

  qkv_gemm<<<dim3(32, 6, 24), 256, 0, stream>>>(
      xs, wqb, wkb, wvb, qbias, kbias, vbias, qg, kg, vtg, cnt64s, idx_all);

  attn2<<<dim3(16, 96, 8), 256, 0, stream>>>(qg, kg, vtg, po, mlm, mll, cnt64s);
  attn_combine<<<dim3(RCAP * NH * 16 / 256), 256, 0, stream>>>(po, mlm, mll, aog, cnt64s);

  // o-proj: split-K x2
  csr_gemm<0><<<dim3(32, 6, 16), 256, 0, stream>>>(
      aog, wob, obias, ooP, NW, NW, 384, 2, NW * NW, ND, cnt64s);

  rmsnorm_res<<<dim3(RCAP), 256, 0, stream>>>(x, ooP, x1b, cnt64s, idx_all);

  // FFN1 (gelu epilogue)
  csr_gemm<2><<<dim3(32, 32, 8), 256, 0, stream>>>(
      x1b, w1b, b1, hb, NF, NW, NW, 1, NF * NW, NF, cnt64s);

  // FFN2: split-K x4
  csr_gemm<0><<<dim3(32, 6, 32), 256, 0, stream>>>(
      hb, w2b, b2, ffp, NW, NF, 1024, 4, NW * NF, ND, cnt64s);

  final_token<<<dim3(NTOK), 256, 0, stream>>>(x1b, ffp, gate, inv, cnt64s, out);
}

// Round 6
// 609.290 us; speedup vs baseline: 2.3921x; 1.9462x over previous
//
#include <hip/hip_runtime.h>
#include <cstdint>

// SlimmableMoE: B=4,S=1024,D=1024,E=8,F=4096,W=768,H=6,HD=128,TOPK=2
#define NE 8
#define NB 4
#define NS 1024
#define ND 1024
#define NF 4096
#define NW 768
#define NH 6
#define NHD 128
#define NTOK 4096   // B*S
#define NBH 24      // B*H
#define RCAP 10496  // compacted-row capacity (max Rtotal=10240 + tile over-read)
#define VSTRIDE ((size_t)NTOK * NW)   // per-expert V^T extent = B*H*HD*S = 3145728
#define EPS 1e-6f

typedef unsigned short ush;
typedef __attribute__((ext_vector_type(8))) short short8;   // 8 bf16 = 4 VGPR
typedef __attribute__((ext_vector_type(4))) float f32x4;
typedef __attribute__((ext_vector_type(4))) unsigned short u16x4;

typedef const __attribute__((address_space(1))) void gvoid_t;
typedef __attribute__((address_space(3))) void lvoid_t;

__device__ __forceinline__ void gload16(const void* g, void* l) {
  __builtin_amdgcn_global_load_lds((gvoid_t*)g, (lvoid_t*)l, 16, 0, 0);
}

__device__ __forceinline__ ush f2b(float f) {
  union { float f; uint32_t u; } x; x.f = f;
  uint32_t r = x.u + 0x7fffu + ((x.u >> 16) & 1u);
  return (ush)(r >> 16);
}
__device__ __forceinline__ float b2f(ush u) {
  union { uint32_t u; float f; } x; x.u = (uint32_t)u << 16;
  return x.f;
}
__device__ __forceinline__ int prefix_sum(const int* __restrict__ c, int n) {
  int s = 0;
#pragma unroll 1
  for (int i = 0; i < n; ++i) s += c[i];
  return s;
}

// ---------------- router: logits->softmax->top2->gate; init inv map ----------------
__global__ __launch_bounds__(256, 4)
void router_kernel(const float* __restrict__ x, const float* __restrict__ wr,
                   float* __restrict__ gate, int* __restrict__ inv) {
  int lane = threadIdx.x & 63, wave = threadIdx.x >> 6;
  int t = blockIdx.x * 4 + wave;
  float acc[NE] = {};
  for (int i = 0; i < 16; ++i) {
    int d = lane + i * 64;
    float xv = x[(size_t)t * ND + d];
    const float* wp = wr + (size_t)d * NE;
    float4 w0 = *(const float4*)wp, w1 = *(const float4*)(wp + 4);
    acc[0] += xv * w0.x; acc[1] += xv * w0.y; acc[2] += xv * w0.z; acc[3] += xv * w0.w;
    acc[4] += xv * w1.x; acc[5] += xv * w1.y; acc[6] += xv * w1.z; acc[7] += xv * w1.w;
  }
#pragma unroll
  for (int e = 0; e < NE; ++e)
    for (int m = 1; m < 64; m <<= 1) acc[e] += __shfl_xor(acc[e], m);
  int i1 = 0; float v1 = acc[0];
#pragma unroll
  for (int e = 1; e < NE; ++e) if (acc[e] > v1) { v1 = acc[e]; i1 = e; }
  int i2 = -1; float v2 = -3.0e38f;
#pragma unroll
  for (int e = 0; e < NE; ++e) if (e != i1 && acc[e] > v2) { v2 = acc[e]; i2 = e; }
  float p2 = __expf(v2 - v1);          // p1 = 1
  float g1 = 1.0f / (1.0f + p2), g2 = p2 / (1.0f + p2);
  if (lane < NE)
    gate[(size_t)t * NE + lane] = (lane == i1) ? g1 : ((lane == i2) ? g2 : 0.0f);
  if (lane < 2) inv[t * 2 + lane] = -1;
}

// ---------------- per-expert routed-token index lists + inverse map ----------------
__global__ __launch_bounds__(1024, 1)
void build_index(const float* __restrict__ gate, int* __restrict__ cnt64s,
                 int* __restrict__ idx_all, int* __restrict__ inv) {
  int e = blockIdx.x >> 2, b = blockIdx.x & 3;
  int s = threadIdx.x, t = b * 1024 + s;
  bool on = gate[(size_t)t * NE + e] > 0.0f;
  idx_all[(e * 4 + b) * 1024 + s] = (b * 1024) | (int)0x80000000;   // pad default
  __shared__ int wsum[16], wbase[16];
  unsigned long long mask = __ballot(on);
  int lane = s & 63, wv = s >> 6;
  if (lane == 0) wsum[wv] = __popcll(mask);
  __syncthreads();
  if (s == 0) {
    int acc = 0;
    for (int i = 0; i < 16; ++i) { wbase[i] = acc; acc += wsum[i]; }
    cnt64s[e * 4 + b] = (acc + 63) & ~63;
  }
  __syncthreads();
  if (on) {
    int pos = wbase[wv] + __popcll(mask & ((1ull << lane) - 1ull));
    idx_all[(e * 4 + b) * 1024 + pos] = t;
    int k = 0;
#pragma unroll
    for (int j = 0; j < NE; ++j) k += (j < e && gate[(size_t)t * NE + j] > 0.0f);
    inv[t * 2 + k] = (e << 12) | pos;
  }
}

// ---------------- all casts f32->bf16 in one launch: y=0..7 expert weights, y=8 xs ----------------
__global__ __launch_bounds__(256, 4)
void cast_all(const float* __restrict__ x,
              const float* __restrict__ qw, const float* __restrict__ kw,
              const float* __restrict__ vw, const float* __restrict__ ow,
              const float* __restrict__ w1, const float* __restrict__ w2,
              ush* __restrict__ xs,
              ush* __restrict__ dq, ush* __restrict__ dk, ush* __restrict__ dv,
              ush* __restrict__ dwo, ush* __restrict__ d1, ush* __restrict__ d2) {
  int y = blockIdx.y;
  if (y == 8) {
    const int n4 = NTOK * NW / 4;
    for (int u = blockIdx.x * 256 + threadIdx.x; u < n4; u += gridDim.x * 256) {
      int r = u / (NW / 4), c = u - r * (NW / 4);
      float4 v = *(const float4*)(x + (size_t)r * ND + c * 4);
      u16x4 o; o.x = f2b(v.x); o.y = f2b(v.y); o.z = f2b(v.z); o.w = f2b(v.w);
      *(u16x4*)(xs + (size_t)u * 4) = o;
    }
    return;
  }
  const int e = y;
  const int Q4 = 147456;   // 768*768/4
  const int W14 = 786432;  // 4096*768/4
  const int total = 4 * Q4 + 2 * W14;
  const float* qe = qw + (size_t)e * ND * ND;
  const float* ke = kw + (size_t)e * ND * ND;
  const float* ve = vw + (size_t)e * ND * ND;
  const float* oe = ow + (size_t)e * ND * ND;
  const float* w1e = w1 + (size_t)e * NF * ND;
  const float* w2e = w2 + (size_t)e * ND * NF;
  ush* dqe = dq + (size_t)e * NW * NW;
  ush* dke = dk + (size_t)e * NW * NW;
  ush* dve = dv + (size_t)e * NW * NW;
  ush* doe = dwo + (size_t)e * NW * NW;
  ush* d1e = d1 + (size_t)e * NF * NW;
  ush* d2e = d2 + (size_t)e * NW * NF;
  for (int u = blockIdx.x * 256 + threadIdx.x; u < total; u += gridDim.x * 256) {
    const float* src; ush* dst; int ldsrc, cols4, rel;
    if (u < 4 * Q4) {
      int which = u / Q4; rel = u - which * Q4;
      src = (which == 0) ? qe : (which == 1) ? ke : (which == 2) ? ve : oe;
      dst = (which == 0) ? dqe : (which == 1) ? dke : (which == 2) ? dve : doe;
      ldsrc = 1024; cols4 = 192;
    } else if (u < 4 * Q4 + W14) {
      rel = u - 4 * Q4; src = w1e; dst = d1e; ldsrc = 1024; cols4 = 192;
    } else {
      rel = u - 4 * Q4 - W14; src = w2e; dst = d2e; ldsrc = 4096; cols4 = 1024;
    }
    int r = rel / cols4, c = rel - r * cols4;
    float4 v = *(const float4*)(src + (size_t)r * ldsrc + (size_t)c * 4);
    u16x4 o; o.x = f2b(v.x); o.y = f2b(v.y); o.z = f2b(v.z); o.w = f2b(v.w);
    *(u16x4*)(dst + (size_t)rel * 4) = o;
  }
}

#define BM 128
#define BN 128
#define BK 64

__device__ __forceinline__ float gelu_exact(float v) {
  return 0.5f * v * (1.0f + erff(v * 0.70710678118654752f));
}

// ---------------- batched QKV GEMM ----------------
// 1-D grid nwg = 8*576; e = bid&7 (XCD-pinned), wi = bid>>3: bn=wi%6, bm=(wi/6)%32, w=wi/192
__global__ __launch_bounds__(256, 3)
void qkv_gemm(const ush* __restrict__ A,
              const ush* __restrict__ wqb, const ush* __restrict__ wkb,
              const ush* __restrict__ wvb,
              const float* __restrict__ qbias, const float* __restrict__ kbias,
              const float* __restrict__ vbias,
              ush* __restrict__ qg, ush* __restrict__ kg, ush* __restrict__ vtg,
              const int* __restrict__ cnt64s, const int* __restrict__ idx_all) {
  const int bid = blockIdx.x;
  const int e = bid & 7, wi = bid >> 3;
  const int bn = wi % 6, bm = (wi / 6) % 32, w = wi / 192;
  int sb = 0, cnt = 0;
  if (w == 0) {
    int sec = e * 4 + (bm >> 3);
    cnt = cnt64s[sec];
    if (((bm & 7) * 128) >= cnt) return;
    sb = prefix_sum(cnt64s, sec);
  }
  const ush* Bw = ((w == 0) ? wqb : (w == 1) ? wkb : wvb) + (size_t)e * NW * NW;
  const float* bias = ((w == 0) ? qbias : (w == 1) ? kbias : vbias) + (size_t)e * ND;

  __shared__ __align__(16) ush As[BM * BK];
  __shared__ __align__(16) ush Bs[BN * BK];

  const int tid = threadIdx.x, lane = tid & 63, wave = tid >> 6;
  const int lr = lane & 15, lg = lane >> 4;
  const int wr = wave >> 1, wc = wave & 1;

  int rowIdx[4];
#pragma unroll
  for (int p = 0; p < 4; ++p) {
    if (w == 0) {
      int lrow = (bm & 7) * 128 + p * 32 + (tid >> 3);
      rowIdx[p] = idx_all[(e * 4 + (bm >> 3)) * 1024 + lrow] & 0x7fffffff;
    } else {
      rowIdx[p] = bm * BM + p * 32 + (tid >> 3);
    }
  }

  f32x4 acc[4][4] = {};
  for (int kt = 0; kt < NW / BK; ++kt) {
    __syncthreads();
#pragma unroll
    for (int p = 0; p < 4; ++p) {
      int o = p * 4096 + tid * 16;
      int row = o >> 7, cb = o & 127;
      int cbs = cb ^ ((row & 7) << 4);
      gload16((const char*)A + ((size_t)rowIdx[p] * NW + (size_t)kt * BK) * 2 + cbs,
              (char*)As + o);
      gload16((const char*)Bw + ((size_t)(bn * BN + row) * NW + (size_t)kt * BK) * 2 + cbs,
              (char*)Bs + o);
    }
    __syncthreads();
#pragma unroll
    for (int kk = 0; kk < 2; ++kk) {
      short8 af[4], bfr[4];
#pragma unroll
      for (int i = 0; i < 4; ++i) {
        int rowa = wr * 64 + i * 16 + lr;
        af[i] = *(const short8*)((const char*)As + rowa * 128 +
                                 (((kk * 64 + lg * 16)) ^ ((rowa & 7) << 4)));
        int rowb = wc * 64 + i * 16 + lr;
        bfr[i] = *(const short8*)((const char*)Bs + rowb * 128 +
                                  (((kk * 64 + lg * 16)) ^ ((rowb & 7) << 4)));
      }
#pragma unroll
      for (int i = 0; i < 4; ++i)
#pragma unroll
        for (int j = 0; j < 4; ++j)
          acc[i][j] = __builtin_amdgcn_mfma_f32_16x16x32_bf16(af[i], bfr[j], acc[i][j], 0, 0, 0);
    }
  }

#pragma unroll
  for (int i = 0; i < 4; ++i) {
    int lm16 = (bm & 7) * 128 + wr * 64 + i * 16;            // Q: section-local 16-row group
    int m0 = bm * BM + wr * 64 + i * 16 + lg * 4;            // dense row
#pragma unroll
    for (int j = 0; j < 4; ++j) {
      int n = bn * BN + wc * 64 + j * 16 + lr;
      float bb = bias[n];
      if (w == 0) {
        if (lm16 < cnt) {
          int grow = sb + lm16 + lg * 4;
#pragma unroll
          for (int r = 0; r < 4; ++r)
            qg[(size_t)(grow + r) * NW + n] = f2b(acc[i][j][r] + bb);
        }
      } else if (w == 1) {
        ush* o = kg + (size_t)e * NTOK * NW;
#pragma unroll
        for (int r = 0; r < 4; ++r)
          o[(size_t)(m0 + r) * NW + n] = f2b(acc[i][j][r] + bb);
      } else {
        int b_ = m0 >> 10, s0 = m0 & 1023, h_ = n >> 7, d = n & 127;
        u16x4 wv_;
#pragma unroll
        for (int r = 0; r < 4; ++r) wv_[r] = f2b(acc[i][j][r] + bb);
        *(u16x4*)(vtg + (size_t)e * VSTRIDE +
                  ((size_t)(b_ * NH + h_) * NHD + d) * NS + s0) = wv_;
      }
    }
  }
}

// ---------------- batched flash attention: 1-D grid 8*1536, e = bid&7 (XCD-pinned) ----------------
__global__ __launch_bounds__(256, 3)
void attn2(const ush* __restrict__ Qg, const ush* __restrict__ Kg,
           const ush* __restrict__ VTg,
           ush* __restrict__ po, float* __restrict__ mlm, float* __restrict__ mll,
           const int* __restrict__ cnt64s) {
  const int bid = blockIdx.x;
  const int e = bid & 7, wi = bid >> 3;
  const int qb = wi & 15, yy = wi >> 4;
  const int bh = yy >> 2, half = yy & 3;
  const int b = bh / NH, h = bh % NH;
  const int sec = e * 4 + b;
  const int cnt = cnt64s[sec];
  if (qb * 64 >= cnt) return;
  const int sb = prefix_sum(cnt64s, sec);

  __shared__ __align__(16) ush Ks[64 * 128];
  __shared__ __align__(16) ush VTs[128 * 64];
  __shared__ __align__(16) ush Ps[4 * 16 * 64];

  const int tid = threadIdx.x, lane = tid & 63, wave = tid >> 6;
  const int lr = lane & 15, lg = lane >> 4;
  const int k0 = half * 256;
  const float cexp = 1.4426950408889634f / sqrtf((float)NHD);

  const ush* Ke = Kg + (size_t)e * NTOK * NW;
  const ush* Ve = VTg + (size_t)e * VSTRIDE;

  int growq = sb + qb * 64 + wave * 16 + lr;
  short8 qf[4];
#pragma unroll
  for (int kk = 0; kk < 4; ++kk)
    qf[kk] = *(const short8*)(Qg + (size_t)growq * NW + h * NHD + kk * 32 + lg * 8);

  f32x4 accv[8] = {};
  float mr[4] = {-3.0e38f, -3.0e38f, -3.0e38f, -3.0e38f};
  float ls[4] = {};

  for (int kt = 0; kt < 4; ++kt) {
    __syncthreads();
#pragma unroll
    for (int p = 0; p < 4; ++p) {
      int o = p * 4096 + tid * 16;
      int row = o >> 8, cb = o & 255;
      gload16((const char*)Ke + ((size_t)(b * NS + k0 + kt * 64 + row) * NW + h * NHD) * 2 +
                  (cb ^ ((row & 7) << 4)),
              (char*)Ks + o);
    }
#pragma unroll
    for (int p = 0; p < 4; ++p) {
      int o = p * 4096 + tid * 16;
      int d = o >> 7, cb = o & 127;
      gload16((const char*)Ve + ((size_t)((b * NH + h) * NHD + d) * NS + k0 + kt * 64) * 2 +
                  (cb ^ ((d & 7) << 4)),
              (char*)VTs + o);
    }
    __syncthreads();

    f32x4 s[4] = {};
#pragma unroll
    for (int kg2 = 0; kg2 < 4; ++kg2)
#pragma unroll
      for (int kk = 0; kk < 4; ++kk) {
        int row = kg2 * 16 + lr;
        short8 kf = *(const short8*)((const char*)Ks + row * 256 +
                                     ((kk * 64 + lg * 16) ^ ((row & 7) << 4)));
        s[kg2] = __builtin_amdgcn_mfma_f32_16x16x32_bf16(qf[kk], kf, s[kg2], 0, 0, 0);
      }

    float mt[4];
#pragma unroll
    for (int r = 0; r < 4; ++r) {
      float m0 = fmaxf(fmaxf(s[0][r], s[1][r]), fmaxf(s[2][r], s[3][r]));
#pragma unroll
      for (int mm = 1; mm < 16; mm <<= 1) m0 = fmaxf(m0, __shfl_xor(m0, mm));
      mt[r] = m0;
    }
    bool need = (mt[0] > mr[0] + 8.f) || (mt[1] > mr[1] + 8.f) ||
                (mt[2] > mr[2] + 8.f) || (mt[3] > mr[3] + 8.f);
    if (__any(need)) {
#pragma unroll
      for (int r = 0; r < 4; ++r) {
        float mn = fmaxf(mr[r], mt[r]);
        float sc = exp2f((mr[r] - mn) * cexp);
        mr[r] = mn; ls[r] *= sc;
#pragma unroll
        for (int dg = 0; dg < 8; ++dg) accv[dg][r] *= sc;
      }
    }

    char* pw = (char*)Ps + wave * 2048;
#pragma unroll
    for (int kg2 = 0; kg2 < 4; ++kg2)
#pragma unroll
      for (int r = 0; r < 4; ++r) {
        float p = exp2f((s[kg2][r] - mr[r]) * cexp);
        ls[r] += p;
        int row = lg * 4 + r;
        *(ush*)(pw + row * 128 + (((kg2 * 16 + lr) * 2) ^ ((row & 7) << 4))) = f2b(p);
      }
    short8 pf[2];
#pragma unroll
    for (int kk2 = 0; kk2 < 2; ++kk2)
      pf[kk2] = *(const short8*)(pw + lr * 128 + ((kk2 * 64 + lg * 16) ^ ((lr & 7) << 4)));

#pragma unroll
    for (int dg = 0; dg < 8; ++dg) {
      int d = dg * 16 + lr;
#pragma unroll
      for (int kk2 = 0; kk2 < 2; ++kk2) {
        short8 vf = *(const short8*)((const char*)VTs + d * 128 +
                                     ((kk2 * 64 + lg * 16) ^ ((d & 7) << 4)));
        accv[dg] = __builtin_amdgcn_mfma_f32_16x16x32_bf16(pf[kk2], vf, accv[dg], 0, 0, 0);
      }
    }
  }

#pragma unroll
  for (int r = 0; r < 4; ++r)
#pragma unroll
    for (int mm = 1; mm < 16; mm <<= 1) ls[r] += __shfl_xor(ls[r], mm);

#pragma unroll
  for (int r = 0; r < 4; ++r) {
    int growr = sb + qb * 64 + wave * 16 + lg * 4 + r;
#pragma unroll
    for (int dg = 0; dg < 8; ++dg)
      po[((size_t)(growr * NH + h) * 4 + half) * NHD + dg * 16 + lr] = f2b(accv[dg][r]);
  }
  if (lr == 0) {
#pragma unroll
    for (int r = 0; r < 4; ++r) {
      int growr = sb + qb * 64 + wave * 16 + lg * 4 + r;
      mlm[(size_t)(growr * NH + h) * 4 + half] = mr[r];
      mll[(size_t)(growr * NH + h) * 4 + half] = ls[r];
    }
  }
}

// ---------------- combine 4 KV-split partials -> AO rows (compacted) ----------------
__global__ __launch_bounds__(256, 4)
void attn_combine(const ush* __restrict__ po, const float* __restrict__ mlm,
                  const float* __restrict__ mll, ush* __restrict__ ao,
                  const int* __restrict__ cnt64s) {
  const float cexp = 1.4426950408889634f / sqrtf((float)NHD);
  int Rtot = prefix_sum(cnt64s, 32);
  int idx = blockIdx.x * 256 + threadIdx.x;
  int row = idx >> 4, dq = idx & 15;
  int grow = row / NH, h = row - grow * NH;
  if (grow >= Rtot) return;
  float m[4], l[4], M = -3.0e38f;
#pragma unroll
  for (int hh = 0; hh < 4; ++hh) {
    m[hh] = mlm[(size_t)row * 4 + hh];
    l[hh] = mll[(size_t)row * 4 + hh];
    M = fmaxf(M, m[hh]);
  }
  float L = 0.0f, w[4];
#pragma unroll
  for (int hh = 0; hh < 4; ++hh) { w[hh] = exp2f((m[hh] - M) * cexp); L += l[hh] * w[hh]; }
  float inv_ = 1.0f / L;
  float o[8] = {};
#pragma unroll
  for (int hh = 0; hh < 4; ++hh) {
    short8 v = *(const short8*)(po + ((size_t)row * 4 + hh) * NHD + dq * 8);
#pragma unroll
    for (int j = 0; j < 8; ++j) o[j] += b2f((ush)v[j]) * w[hh];
  }
  short8 res;
#pragma unroll
  for (int j = 0; j < 8; ++j) res[j] = (short)f2b(o[j] * inv_);
  *(short8*)(ao + (size_t)grow * NW + h * NHD + dq * 8) = res;
}

// ---------------- CSR GEMM (batched over experts + optional split-K) ----------------
// 1-D grid nwg = 8 * (nbn*nbm*nsplit); e = bid&7 (XCD-pinned);
// wi = bid>>3: bn = wi%nbn, bm = (wi/nbn)%nbm, s = wi/(nbn*nbm)
template <int EPI>   // 0 = bf16 out, 2 = gelu->bf16
__global__ __launch_bounds__(256, 3)
void csr_gemm(const ush* __restrict__ A, const ush* __restrict__ Ball,
              const float* __restrict__ biasAll, ush* __restrict__ out,
              int N, int Kld, int klen, int nbn, int nbm, int nsplit,
              int strideBe, int biasStride,
              const int* __restrict__ cnt64s) {
  const int bid = blockIdx.x;
  const int e = bid & 7, wi = bid >> 3;
  const int bn = wi % nbn, bm = (wi / nbn) % nbm, s = wi / (nbn * nbm);
  const int Re = cnt64s[e * 4] + cnt64s[e * 4 + 1] + cnt64s[e * 4 + 2] + cnt64s[e * 4 + 3];
  if (bm * BM >= Re) return;
  const int ebase = prefix_sum(cnt64s, e * 4);
  const ush* Bw = Ball + (size_t)e * strideBe;
  const float* bias = (s == 0) ? biasAll + (size_t)e * biasStride : nullptr;
  const int koff = s * klen;
  ush* outp = out + (size_t)s * RCAP * N;

  __shared__ __align__(16) ush As[BM * BK];
  __shared__ __align__(16) ush Bs[BN * BK];

  const int tid = threadIdx.x, lane = tid & 63, wave = tid >> 6;
  const int lr = lane & 15, lg = lane >> 4;
  const int wr = wave >> 1, wc = wave & 1;

  f32x4 acc[4][4] = {};
  const int nkt = klen / BK;
  for (int kt = 0; kt < nkt; ++kt) {
    __syncthreads();
#pragma unroll
    for (int p = 0; p < 4; ++p) {
      int o = p * 4096 + tid * 16;
      int row = o >> 7, cb = o & 127;
      int cbs = cb ^ ((row & 7) << 4);
      gload16((const char*)A + ((size_t)(ebase + bm * BM + row) * Kld + koff + (size_t)kt * BK) * 2 + cbs,
              (char*)As + o);
      gload16((const char*)Bw + ((size_t)(bn * BN + row) * Kld + koff + (size_t)kt * BK) * 2 + cbs,
              (char*)Bs + o);
    }
    __syncthreads();
#pragma unroll
    for (int kk = 0; kk < 2; ++kk) {
      short8 af[4], bfr[4];
#pragma unroll
      for (int i = 0; i < 4; ++i) {
        int rowa = wr * 64 + i * 16 + lr;
        af[i] = *(const short8*)((const char*)As + rowa * 128 +
                                 (((kk * 64 + lg * 16)) ^ ((rowa & 7) << 4)));
        int rowb = wc * 64 + i * 16 + lr;
        bfr[i] = *(const short8*)((const char*)Bs + rowb * 128 +
                                  (((kk * 64 + lg * 16)) ^ ((rowb & 7) << 4)));
      }
#pragma unroll
      for (int i = 0; i < 4; ++i)
#pragma unroll
        for (int j = 0; j < 4; ++j)
          acc[i][j] = __builtin_amdgcn_mfma_f32_16x16x32_bf16(af[i], bfr[j], acc[i][j], 0, 0, 0);
    }
  }

#pragma unroll
  for (int i = 0; i < 4; ++i) {
    int lm16 = bm * BM + wr * 64 + i * 16;
    if (lm16 >= Re) continue;                  // cross-expert guard (Re % 64 == 0)
#pragma unroll
    for (int j = 0; j < 4; ++j) {
      int n = bn * BN + wc * 64 + j * 16 + lr;
      float bb = bias ? bias[n] : 0.0f;
      int row0 = ebase + lm16 + lg * 4;
#pragma unroll
      for (int r = 0; r < 4; ++r) {
        float v = acc[i][j][r] + bb;
        if (EPI == 2) v = gelu_exact(v);
        outp[(size_t)(row0 + r) * N + n] = f2b(v);
      }
    }
  }
}

// ---------------- residual + RMSNorm over compacted rows ----------------
__global__ __launch_bounds__(256, 4)
void rmsnorm_res(const float* __restrict__ x, const ush* __restrict__ ooP,
                 ush* __restrict__ x1b, const int* __restrict__ cnt64s,
                 const int* __restrict__ idx_all) {
  int r = blockIdx.x;
  int base = 0, sec = -1, loc = 0;
#pragma unroll 1
  for (int i = 0; i < 32; ++i) {
    int cc = cnt64s[i];
    if (sec < 0 && r < base + cc) { sec = i; loc = r - base; }
    base += cc;
  }
  if (sec < 0) return;
  int t = idx_all[sec * 1024 + loc] & 0x7fffffff;
  __shared__ float red[4];
  int c = threadIdx.x, lane = c & 63, wave = c >> 6;
  float v[3]; float ss = 0.0f;
#pragma unroll
  for (int i = 0; i < 3; ++i) {
    int col = c + i * 256;
    float a = x[(size_t)t * ND + col] + b2f(ooP[(size_t)r * NW + col]) +
              b2f(ooP[(size_t)RCAP * NW + (size_t)r * NW + col]);
    v[i] = a; ss += a * a;
  }
#pragma unroll
  for (int m = 1; m < 64; m <<= 1) ss += __shfl_xor(ss, m);
  if (lane == 0) red[wave] = ss;
  __syncthreads();
  float tot = red[0] + red[1] + red[2] + red[3];
  float scale = rsqrtf(tot / (float)NW + EPS);
#pragma unroll
  for (int i = 0; i < 3; ++i) {
    int col = c + i * 256;
    x1b[(size_t)r * NW + col] = f2b(v[i] * scale);
  }
}

// ---------------- final: per token, gather both experts, rmsnorm, gate-sum, write out ----------------
__global__ __launch_bounds__(256, 4)
void final_token(const ush* __restrict__ x1b, const ush* __restrict__ ffp,
                 const float* __restrict__ gate, const int* __restrict__ inv,
                 const int* __restrict__ cnt64s, float* __restrict__ out) {
  int t = blockIdx.x, c = threadIdx.x, lane = c & 63, wave = c >> 6;
  __shared__ float red[4];
  float acc[3] = {0.0f, 0.0f, 0.0f};
#pragma unroll 1
  for (int k = 0; k < 2; ++k) {
    int v = inv[t * 2 + k];
    if (v >= 0) {
      int e = v >> 12, pos = v & 0xfff;
      int b = t >> 10;
      int grow = prefix_sum(cnt64s, e * 4 + b) + pos;
      float g = gate[(size_t)t * NE + e];
      float vv[3]; float ss = 0.0f;
#pragma unroll
      for (int i = 0; i < 3; ++i) {
        int col = c + i * 256;
        float f = b2f(ffp[(size_t)grow * NW + col]) +
                  b2f(ffp[(size_t)RCAP * NW + (size_t)grow * NW + col]) +
                  b2f(ffp[2 * (size_t)RCAP * NW + (size_t)grow * NW + col]) +
                  b2f(ffp[3 * (size_t)RCAP * NW + (size_t)grow * NW + col]);
        float a = b2f(x1b[(size_t)grow * NW + col]) + f;
        vv[i] = a; ss += a * a;
      }
#pragma unroll
      for (int m = 1; m < 64; m <<= 1) ss += __shfl_xor(ss, m);
      if (lane == 0) red[wave] = ss;
      __syncthreads();
      float tot = red[0] + red[1] + red[2] + red[3];
      float scale = rsqrtf(tot / (float)NW + EPS) * g;
#pragma unroll
      for (int i = 0; i < 3; ++i) acc[i] += vv[i] * scale;
      __syncthreads();
    }
  }
#pragma unroll
  for (int i = 0; i < 3; ++i) out[(size_t)t * ND + c + i * 256] = acc[i];
  out[(size_t)t * ND + 768 + c] = 0.0f;
}

// ---------------- host ----------------
extern "C" void kernel_launch(void* const* d_in, const int* in_sizes, int n_in,
                              void* d_out, int out_size, void* d_ws, size_t ws_size,
                              hipStream_t stream) {
  (void)in_sizes; (void)n_in; (void)ws_size; (void)out_size;
  const float* x  = (const float*)d_in[0];
  const float* wr = (const float*)d_in[1];
  const float* qw = (const float*)d_in[2];
  const float* qbias = (const float*)d_in[3];
  const float* kw = (const float*)d_in[4];
  const float* kbias = (const float*)d_in[5];
  const float* vw = (const float*)d_in[6];
  const float* vbias = (const float*)d_in[7];
  const float* ow = (const float*)d_in[8];
  const float* obias = (const float*)d_in[9];
  const float* w1 = (const float*)d_in[10];
  const float* b1 = (const float*)d_in[11];
  const float* w2 = (const float*)d_in[12];
  const float* b2 = (const float*)d_in[13];
  float* out = (float*)d_out;
  char* ws = (char*)d_ws;

  size_t off = 0;
  auto alloc = [&](size_t bytes) {
    void* p = ws + off;
    off += (bytes + 255) & ~(size_t)255;
    return p;
  };
  float* gate = (float*)alloc((size_t)NTOK * NE * 4);
  int* cnt64s = (int*)alloc(32 * 4);
  int* idx_all = (int*)alloc((size_t)NE * NTOK * 4);
  int* inv = (int*)alloc((size_t)NTOK * 2 * 4);
  ush* xs  = (ush*)alloc((size_t)NTOK * NW * 2);
  ush* wqb = (ush*)alloc((size_t)NE * NW * NW * 2);
  ush* wkb = (ush*)alloc((size_t)NE * NW * NW * 2);
  ush* wvb = (ush*)alloc((size_t)NE * NW * NW * 2);
  ush* wob = (ush*)alloc((size_t)NE * NW * NW * 2);
  ush* w1b = (ush*)alloc((size_t)NE * NF * NW * 2);
  ush* w2b = (ush*)alloc((size_t)NE * NW * NF * 2);
  ush* x1b = (ush*)alloc((size_t)RCAP * NW * 2);
  // arena1: attn {qg, po, mlm, mll} -> ffn {hb}
  char* arena1 = (char*)alloc((size_t)RCAP * NF * 2);          // 86.0 MB
  ush* qg  = (ush*)arena1;                                      // RCAP*768*2 = 16.1 MB
  ush* po  = (ush*)(arena1 + 16121856);                         // RCAP*24*128*2 = 64.5 MB
  float* mlm = (float*)(arena1 + 80609280);                     // RCAP*24*4 = 1.0 MB
  float* mll = (float*)(arena1 + 81616896);
  ush* hb  = (ush*)arena1;                                      // RCAP*4096*2
  // arena2: attn {kg, vtg} -> post {aog, ooP, ffp}
  char* arena2 = (char*)alloc(112852992);
  ush* kg  = (ush*)arena2;                                      // 8*4096*768*2 = 50.3 MB
  ush* vtg = (ush*)(arena2 + 50331648);                         // 50.3 MB
  ush* aog = (ush*)arena2;                                      // RCAP*768*2
  ush* ooP = (ush*)(arena2 + 16121856);                         // 2 partials
  ush* ffp = (ush*)(arena2 + 48365568);                         // 4 partials

  router_kernel<<<dim3(NTOK / 4), 256, 0, stream>>>(x, wr, gate, inv);
  build_index<<<dim3(NE * NB), 1024, 0, stream>>>(gate, cnt64s, idx_all, inv);
  cast_all<<<dim3(288, 9), 256, 0, stream>>>(x, qw, kw, vw, ow, w1, w2,
                                             xs, wqb, wkb, wvb, wob, w1b, w2b);

  // QKV: 8 experts XCD-pinned; per-expert 576 blocks (bn 6 x bm 32 x w 3)
  qkv_gemm<<<dim3(8 * 576), 256, 0, stream>>>(
      xs, wqb, wkb, wvb, qbias, kbias, vbias, qg, kg, vtg, cnt64s, idx_all);

  // attention: per-expert 1536 blocks (qb 16 x yy 96)
  attn2<<<dim3(8 * 1536), 256, 0, stream>>>(qg, kg, vtg, po, mlm, mll, cnt64s);
  attn_combine<<<dim3(RCAP * NH * 16 / 256), 256, 0, stream>>>(po, mlm, mll, aog, cnt64s);

  // o-proj: split-K x2; per-expert 384 blocks (bn 6 x bm 32 x s 2)
  csr_gemm<0><<<dim3(8 * 384), 256, 0, stream>>>(
      aog, wob, obias, ooP, NW, NW, 384, 6, 32, 2, NW * NW, ND, cnt64s);

  rmsnorm_res<<<dim3(RCAP), 256, 0, stream>>>(x, ooP, x1b, cnt64s, idx_all);

  // FFN1 (gelu): per-expert 1024 blocks (bn 32 x bm 32)
  csr_gemm<2><<<dim3(8 * 1024), 256, 0, stream>>>(
      x1b, w1b, b1, hb, NF, NW, NW, 32, 32, 1, NF * NW, NF, cnt64s);

  // FFN2: split-K x4; per-expert 768 blocks (bn 6 x bm 32 x s 4)
  csr_gemm<0><<<dim3(8 * 768), 256, 0, stream>>>(
      hb, w2b, b2, ffp, NW, NF, 1024, 6, 32, 4, NW * NF, ND, cnt64s);

  final_token<<<dim3(NTOK), 256, 0, stream>>>(x1b, ffp, gate, inv, cnt64s, out);
}